// Round 11
// baseline (121.933 us; speedup 1.0000x reference)
//
#include <hip/hip_runtime.h>

#define NTOK 1600
#define BT_TOTAL 8
#define INNER 128
#define HD 32
#define NH 4
#define QDIM 256

typedef short short8 __attribute__((ext_vector_type(8)));
typedef short short4v __attribute__((ext_vector_type(4)));
typedef float f32x2 __attribute__((ext_vector_type(2)));
typedef float f32x4 __attribute__((ext_vector_type(4)));
typedef float f32x16 __attribute__((ext_vector_type(16)));
typedef unsigned uint2v __attribute__((ext_vector_type(2)));

__device__ inline short f2b(float x) {  // fp32 -> bf16, RNE-ish
  union { float f; unsigned u; } v; v.f = x;
  unsigned r = (v.u + 0x7FFF + ((v.u >> 16) & 1)) >> 16;
  return (short)r;
}
// packed bf16 convert: lo16 = bf16(a), hi16 = bf16(b), RNE, single VALU op
__device__ inline unsigned cvtpk(float a, float b) {
  unsigned r;
  asm("v_cvt_pk_bf16_f32 %0, %1, %2" : "=v"(r) : "v"(a), "v"(b));
  return r;
}
// v_permlane32_swap_b32: block-transpose primitive.
//   a' = {lanes 0-31: a[0:31],  lanes 32-63: b[0:31]}
//   b' = {lanes 0-31: a[32:63], lanes 32-63: b[32:63]}
__device__ inline void pswap(unsigned &a, unsigned &b) {
  uint2v r = __builtin_amdgcn_permlane32_swap(a, b, false, false);
  a = r[0]; b = r[1];
}
// LDS fragment load from 8B-aligned rows (stride 36 shorts): two b64 reads
__device__ inline short8 ldsfrag(const short* p) {
  short4v a = *(const short4v*)p;
  short4v b = *(const short4v*)(p + 4);
  short8 r;
  r[0] = a[0]; r[1] = a[1]; r[2] = a[2]; r[3] = a[3];
  r[4] = b[0]; r[5] = b[1]; r[6] = b[2]; r[7] = b[3];
  return r;
}
__device__ inline short8 mk8(unsigned a, unsigned b, unsigned c, unsigned d) {
  union { unsigned u[4]; short8 v; } t;
  t.u[0] = a; t.u[1] = b; t.u[2] = c; t.u[3] = d;
  return t.v;
}

// ---- fused QKV projection (MFMA), register-prefetched staging (R6) --------
// which=0: Q (scaled by 1/sqrt(32)*log2(e)) token-major [bt][h][tok][32]
// which=1: K token-major [bt][h][tok][32]
// which=2: V d-major [bt][i][tok]
__global__ __launch_bounds__(256) void proj_fused(
    const float* __restrict__ query, const float* __restrict__ Wq,
    const float* __restrict__ key, const float* __restrict__ Wk,
    const float* __restrict__ value, const float* __restrict__ Wv,
    short* __restrict__ Qbf, short* __restrict__ Kbf,
    short* __restrict__ Vbf) {
  const int n0 = blockIdx.x * 64;
  const int which = blockIdx.y;
  const int bt = blockIdx.z;
  const int t = threadIdx.x;
  const int lane = t & 63, w = t >> 6;
  const int quad = lane >> 4, n16 = lane & 15;

  const float* X; const float* Wt; short* Y; int nchunk; float scl;
  if (which == 0) {
    X = query; Wt = Wq; Y = Qbf; nchunk = 8;
    scl = 0.17677669529663687f * 1.4426950408889634f;  // fold log2(e)
  } else if (which == 1) {
    X = key; Wt = Wk; Y = Kbf; nchunk = 4; scl = 1.0f;
  } else {
    X = value; Wt = Wv; Y = Vbf; nchunk = 4; scl = 1.0f;
  }
  const float* Xb = X + (size_t)bt * (nchunk * 32) * NTOK;

  __shared__ short Xs[64 * 36];   // [tok][d] bf16
  __shared__ short Ws[128 * 36];  // [i][d] bf16

  f32x4 acc[8];
#pragma unroll
  for (int i = 0; i < 8; ++i) acc[i] = (f32x4){0.f, 0.f, 0.f, 0.f};

  const int iw = t & 127, g = t >> 7;

  float xf0[4], xf1[4], wf0[8], wf1[8];
  auto loadX = [&](int cd) {
#pragma unroll
    for (int dp = 0; dp < 4; ++dp) {
      int dl = w * 8 + dp * 2;
      xf0[dp] = Xb[(size_t)(cd + dl) * NTOK + n0 + lane];
      xf1[dp] = Xb[(size_t)(cd + dl + 1) * NTOK + n0 + lane];
    }
  };
  auto loadW = [&](int cd) {
#pragma unroll
    for (int dp = 0; dp < 8; ++dp) {
      int dl = g * 16 + dp * 2;
      wf0[dp] = Wt[(size_t)(cd + dl) * INNER + iw];
      wf1[dp] = Wt[(size_t)(cd + dl + 1) * INNER + iw];
    }
  };
  loadX(0); loadW(0);

  for (int c = 0; c < nchunk; ++c) {
#pragma unroll
    for (int dp = 0; dp < 4; ++dp)
      *(unsigned*)&Xs[lane * 36 + w * 8 + dp * 2] = cvtpk(xf0[dp], xf1[dp]);
#pragma unroll
    for (int dp = 0; dp < 8; ++dp)
      *(unsigned*)&Ws[iw * 36 + g * 16 + dp * 2] = cvtpk(wf0[dp], wf1[dp]);
    __syncthreads();
    if (c + 1 < nchunk) { loadX((c + 1) * 32); loadW((c + 1) * 32); }
    if (which != 2) {
      short8 a[4], b[2];
#pragma unroll
      for (int tg = 0; tg < 4; ++tg)
        a[tg] = ldsfrag(&Xs[(tg * 16 + n16) * 36 + quad * 8]);
#pragma unroll
      for (int cg = 0; cg < 2; ++cg)
        b[cg] = ldsfrag(&Ws[(w * 32 + cg * 16 + n16) * 36 + quad * 8]);
#pragma unroll
      for (int tg = 0; tg < 4; ++tg)
#pragma unroll
        for (int cg = 0; cg < 2; ++cg)
          acc[tg * 2 + cg] = __builtin_amdgcn_mfma_f32_16x16x32_bf16(
              a[tg], b[cg], acc[tg * 2 + cg], 0, 0, 0);
    } else {
      short8 a[2], b[4];
#pragma unroll
      for (int ig = 0; ig < 2; ++ig)
        a[ig] = ldsfrag(&Ws[(w * 32 + ig * 16 + n16) * 36 + quad * 8]);
#pragma unroll
      for (int tg = 0; tg < 4; ++tg)
        b[tg] = ldsfrag(&Xs[(tg * 16 + n16) * 36 + quad * 8]);
#pragma unroll
      for (int ig = 0; ig < 2; ++ig)
#pragma unroll
        for (int tg = 0; tg < 4; ++tg)
          acc[ig * 4 + tg] = __builtin_amdgcn_mfma_f32_16x16x32_bf16(
              a[ig], b[tg], acc[ig * 4 + tg], 0, 0, 0);
    }
    __syncthreads();
  }

  if (which != 2) {
    short* Yb = Y + ((size_t)bt * NH + w) * NTOK * HD;
#pragma unroll
    for (int tg = 0; tg < 4; ++tg)
#pragma unroll
      for (int cg = 0; cg < 2; ++cg) {
        f32x4 a = acc[tg * 2 + cg];
#pragma unroll
        for (int r = 0; r < 4; ++r) {
          int tok = n0 + tg * 16 + quad * 4 + r;
          Yb[(size_t)tok * HD + cg * 16 + n16] = f2b(a[r] * scl);
        }
      }
  } else {
#pragma unroll
    for (int ig = 0; ig < 2; ++ig)
#pragma unroll
      for (int tg = 0; tg < 4; ++tg) {
        f32x4 a = acc[ig * 4 + tg];
#pragma unroll
        for (int r = 0; r < 4; ++r) {
          int irow = w * 32 + ig * 16 + quad * 4 + r;
          Y[((size_t)bt * INNER + irow) * NTOK + n0 + tg * 16 + n16] =
              f2b(a[r]);
        }
      }
  }
}

// ---- MFMA attention, 32x32 shape, two q-tiles, depth-2 K/V prefetch -------
// grid 800: id>>5 = 64-q tile (25), id&31 = (bt,h); bid%8 = pair%8 keeps
// each pair's K/V XCD-local. Wave w covers k-range (416/416/384/384).
// Two 32-q tiles share one K/V stream (work/chunk ~310 cyc, R6-verified).
// NEW vs R6: 3-buffer rotating prefetch, lookahead 2 -> ~620 cyc between
// load-issue and first use, covering the L3/remote-L2 latency (~450-600
// cyc) that the proj->attn kernel boundary forces on first-touch K/V
// (written by other XCDs; depth-1's 310 cyc was not enough -- attn ran
// ~3x its issue-bound floor). #pragma unroll 3 lets register renaming
// absorb the buffer rotation. K-split combine via 17 KB LDS, two stages.
__global__ __launch_bounds__(256, 3) void attn_mfma(
    const short* __restrict__ Qb, const short* __restrict__ Kb,
    const short* __restrict__ Vb, short* __restrict__ Obf) {
  const int id = blockIdx.x;
  const int qt = id >> 5;
  const int pair = id & 31;
  const int bt = pair >> 2, h = pair & 3;
  const int wave = threadIdx.x >> 6, lane = threadIdx.x & 63;
  const int lh = lane >> 5, q32 = lane & 31;
  const int q0 = qt * 64;
  const size_t btok = ((size_t)bt * NH + h) * NTOK;
  const size_t bd = ((size_t)bt * NH + h) * HD;

  __shared__ float Cb[2][2][17][64];  // [tile][stage][row][lane], 17.4 KB

  const short* QpA = &Qb[(btok + q0 + q32) * HD + lh * 8];
  const short* QpB = QpA + 32 * HD;
  const short8 bqA0 = *(const short8*)(QpA);
  const short8 bqA1 = *(const short8*)(QpA + 16);
  const short8 bqB0 = *(const short8*)(QpB);
  const short8 bqB1 = *(const short8*)(QpB + 16);

  const int kstart = wave * 416 - (wave == 3 ? 32 : 0);
  const int nch = 13 - (wave >> 1);
  const short* Kp = &Kb[(btok + kstart + q32) * HD + lh * 8];
  const short* Vp = &Vb[(bd + q32) * NTOK + kstart + lh * 8];

  const f32x16 zero16 = {0.f, 0.f, 0.f, 0.f, 0.f, 0.f, 0.f, 0.f,
                         0.f, 0.f, 0.f, 0.f, 0.f, 0.f, 0.f, 0.f};
  f32x16 oA = zero16, oB = zero16;
  f32x2 lsA = {0.f, 0.f}, lsB = {0.f, 0.f};

  // exp2 + pack + cross-half exchange: S^T[k][q] regs -> PV B-operand frags.
  // reg r of sv holds S^T[k][q32], k = (r&3) + 8*(r>>2) + 4*lh.
  auto softmax_pack = [&](const f32x16& sv, f32x2& ls2, short8& pb0,
                          short8& pb1) {
    unsigned Pd[8];
#pragma unroll
    for (int g = 0; g < 4; ++g) {
      float e0 = __builtin_amdgcn_exp2f(sv[4 * g + 0]);
      float e1 = __builtin_amdgcn_exp2f(sv[4 * g + 1]);
      float e2 = __builtin_amdgcn_exp2f(sv[4 * g + 2]);
      float e3 = __builtin_amdgcn_exp2f(sv[4 * g + 3]);
      ls2 += (f32x2){e0, e1};
      ls2 += (f32x2){e2, e3};
      Pd[2 * g + 0] = cvtpk(e0, e1);
      Pd[2 * g + 1] = cvtpk(e2, e3);
    }
    // pswap(a,b): a.row1 <-> b.row0 =>
    //  Pd[0]' = {lo: own k0k1,        hi: lo-half's k8k9 }  = B dword0
    //  Pd[2]' = {lo: hi-half's k4k5,  hi: own k12k13     }  = B dword2
    pswap(Pd[0], Pd[2]);
    pswap(Pd[1], Pd[3]);
    pswap(Pd[4], Pd[6]);
    pswap(Pd[5], Pd[7]);
    pb0 = mk8(Pd[0], Pd[1], Pd[2], Pd[3]);
    pb1 = mk8(Pd[4], Pd[5], Pd[6], Pd[7]);
  };

  // 3-set rotating K/V buffers, lookahead 2 (chunk i uses cur; nx1 = i+1;
  // nx2 issued for i+2). OOB lookahead wraps to chunk 0 (values discarded).
  short8 cK0 = *(const short8*)(Kp);
  short8 cK1 = *(const short8*)(Kp + 16);
  short8 cV0 = *(const short8*)(Vp);
  short8 cV1 = *(const short8*)(Vp + 16);
  const size_t k1 = (1 < nch) ? (size_t)32 : 0;
  short8 n1K0 = *(const short8*)(Kp + k1 * HD);
  short8 n1K1 = *(const short8*)(Kp + k1 * HD + 16);
  short8 n1V0 = *(const short8*)(Vp + k1);
  short8 n1V1 = *(const short8*)(Vp + k1 + 16);

#pragma unroll 3
  for (int i = 0; i < nch; ++i) {
    const size_t kn = (i + 2 < nch) ? (size_t)(i + 2) * 32 : 0;
    short8 n2K0 = *(const short8*)(Kp + kn * HD);
    short8 n2K1 = *(const short8*)(Kp + kn * HD + 16);
    short8 n2V0 = *(const short8*)(Vp + kn);
    short8 n2V1 = *(const short8*)(Vp + kn + 16);

    {  // tile A
      f32x16 s = __builtin_amdgcn_mfma_f32_32x32x16_bf16(cK0, bqA0, zero16,
                                                         0, 0, 0);
      s = __builtin_amdgcn_mfma_f32_32x32x16_bf16(cK1, bqA1, s, 0, 0, 0);
      short8 pb0, pb1;
      softmax_pack(s, lsA, pb0, pb1);
      oA = __builtin_amdgcn_mfma_f32_32x32x16_bf16(cV0, pb0, oA, 0, 0, 0);
      oA = __builtin_amdgcn_mfma_f32_32x32x16_bf16(cV1, pb1, oA, 0, 0, 0);
    }
    {  // tile B
      f32x16 s = __builtin_amdgcn_mfma_f32_32x32x16_bf16(cK0, bqB0, zero16,
                                                         0, 0, 0);
      s = __builtin_amdgcn_mfma_f32_32x32x16_bf16(cK1, bqB1, s, 0, 0, 0);
      short8 pb0, pb1;
      softmax_pack(s, lsB, pb0, pb1);
      oB = __builtin_amdgcn_mfma_f32_32x32x16_bf16(cV0, pb0, oB, 0, 0, 0);
      oB = __builtin_amdgcn_mfma_f32_32x32x16_bf16(cV1, pb1, oB, 0, 0, 0);
    }

    cK0 = n1K0; cK1 = n1K1; cV0 = n1V0; cV1 = n1V1;
    n1K0 = n2K0; n1K1 = n2K1; n1V0 = n2V0; n1V1 = n2V1;
  }

  float lsumA = lsA[0] + lsA[1];
  lsumA += __shfl_xor(lsumA, 32);  // full row sum over both halves
  float lsumB = lsB[0] + lsB[1];
  lsumB += __shfl_xor(lsumB, 32);

  // two-stage combine across waves (17 KB LDS), both tiles in parallel
  auto dump = [&](int tl, int sidx, const f32x16& o, float ls) {
#pragma unroll
    for (int r = 0; r < 16; ++r) Cb[tl][sidx][r][lane] = o[r];
    Cb[tl][sidx][16][lane] = ls;
  };
  auto accum = [&](int tl, int sidx, f32x16& o, float& ls) {
#pragma unroll
    for (int r = 0; r < 16; ++r) o[r] += Cb[tl][sidx][r][lane];
    ls += Cb[tl][sidx][16][lane];
  };
  if (wave == 1) { dump(0, 0, oA, lsumA); dump(1, 0, oB, lsumB); }
  if (wave == 3) { dump(0, 1, oA, lsumA); dump(1, 1, oB, lsumB); }
  __syncthreads();
  if (wave == 0) { accum(0, 0, oA, lsumA); accum(1, 0, oB, lsumB); }
  if (wave == 2) { accum(0, 1, oA, lsumA); accum(1, 1, oB, lsumB); }
  __syncthreads();
  if (wave == 2) { dump(0, 0, oA, lsumA); dump(1, 0, oB, lsumB); }
  __syncthreads();
  if (wave == 0) {
    accum(0, 0, oA, lsumA);
    accum(1, 0, oB, lsumB);
    // O^T C-layout: col q = q32, row d = (r&3)+8*(r>>2)+4*lh
    const float invA = 1.f / lsumA;
    short* OpA =
        &Obf[((size_t)bt * NTOK + q0 + q32) * INNER + h * HD + lh * 4];
#pragma unroll
    for (int g = 0; g < 4; ++g) {
      unsigned d0 = cvtpk(oA[4 * g + 0] * invA, oA[4 * g + 1] * invA);
      unsigned d1 = cvtpk(oA[4 * g + 2] * invA, oA[4 * g + 3] * invA);
      *(uint2*)&OpA[8 * g] = make_uint2(d0, d1);
    }
    const float invB = 1.f / lsumB;
    short* OpB =
        &Obf[((size_t)bt * NTOK + q0 + 32 + q32) * INNER + h * HD + lh * 4];
#pragma unroll
    for (int g = 0; g < 4; ++g) {
      unsigned d0 = cvtpk(oB[4 * g + 0] * invB, oB[4 * g + 1] * invB);
      unsigned d1 = cvtpk(oB[4 * g + 2] * invB, oB[4 * g + 3] * invB);
      *(uint2*)&OpB[8 * g] = make_uint2(d0, d1);
    }
  }
}

// ---- output projection (MFMA). grid (25, 4, 8): 64 tok x 64 dout tiles ----
__global__ __launch_bounds__(256) void oproj_mfma(
    const short* __restrict__ Obf, const float* __restrict__ Wo,
    const float* __restrict__ bo, float* __restrict__ out) {
  const int tok0 = blockIdx.x * 64, d0 = blockIdx.y * 64;
  const int bt = blockIdx.z;
  const int t = threadIdx.x, lane = t & 63, w = t >> 6;
  const int quad = lane >> 4, n16 = lane & 15;
  __shared__ short Wos[64 * 36];  // [dout][i] bf16
  f32x4 acc[4];
#pragma unroll
  for (int i = 0; i < 4; ++i) acc[i] = (f32x4){0.f, 0.f, 0.f, 0.f};
  const int tok = tok0 + w * 16 + n16;  // always < 1600

  float wf0[4], wf1[4];
  short8 bfr;
  auto loadWo = [&](int c) {
#pragma unroll
    for (int dp = 0; dp < 4; ++dp) {
      int il = w * 8 + dp * 2;
      wf0[dp] = Wo[(size_t)(c * 32 + il) * QDIM + d0 + lane];
      wf1[dp] = Wo[(size_t)(c * 32 + il + 1) * QDIM + d0 + lane];
    }
  };
  auto loadB = [&](int c) {
    bfr = *(const short8*)&Obf[((size_t)bt * NTOK + tok) * INNER + c * 32 +
                               quad * 8];
  };
  loadWo(0); loadB(0);

  for (int c = 0; c < 4; ++c) {
#pragma unroll
    for (int dp = 0; dp < 4; ++dp)
      *(unsigned*)&Wos[lane * 36 + w * 8 + dp * 2] = cvtpk(wf0[dp], wf1[dp]);
    __syncthreads();
    short8 b0 = bfr;
    if (c < 3) { loadWo(c + 1); loadB(c + 1); }
#pragma unroll
    for (int ag = 0; ag < 4; ++ag) {
      short8 a = ldsfrag(&Wos[(ag * 16 + n16) * 36 + quad * 8]);
      acc[ag] = __builtin_amdgcn_mfma_f32_16x16x32_bf16(a, b0, acc[ag], 0, 0, 0);
    }
    __syncthreads();
  }

#pragma unroll
  for (int ag = 0; ag < 4; ++ag) {
    f32x4 a = acc[ag];
#pragma unroll
    for (int r = 0; r < 4; ++r) {
      int dout = d0 + ag * 16 + quad * 4 + r;
      out[((size_t)bt * QDIM + dout) * NTOK + tok] = a[r] + bo[dout];
    }
  }
}

extern "C" void kernel_launch(void* const* d_in, const int* in_sizes, int n_in,
                              void* d_out, int out_size, void* d_ws,
                              size_t ws_size, hipStream_t stream) {
  const float* query = (const float*)d_in[0];
  const float* key = (const float*)d_in[1];
  const float* value = (const float*)d_in[2];
  const float* Wq = (const float*)d_in[3];
  const float* Wk = (const float*)d_in[4];
  const float* Wv = (const float*)d_in[5];
  const float* Wo = (const float*)d_in[6];
  const float* bo = (const float*)d_in[7];
  float* out = (float*)d_out;

  const size_t arr = (size_t)BT_TOTAL * INNER * NTOK;
  short* Qbf = (short*)d_ws;
  short* Kbf = Qbf + arr;
  short* Vbf = Kbf + arr;
  short* Obf = Vbf + arr;

  proj_fused<<<dim3(25, 3, BT_TOTAL), 256, 0, stream>>>(
      query, Wq, key, Wk, value, Wv, Qbf, Kbf, Vbf);
  attn_mfma<<<dim3(800), 256, 0, stream>>>(Qbf, Kbf, Vbf, Obf);
  oproj_mfma<<<dim3(25, 4, BT_TOTAL), 256, 0, stream>>>(Obf, Wo, bo, out);
}

// Round 12
// 120.049 us; speedup vs baseline: 1.0157x; 1.0157x over previous
//
#include <hip/hip_runtime.h>

#define NTOK 1600
#define BT_TOTAL 8
#define INNER 128
#define HD 32
#define NH 4
#define QDIM 256

typedef short short8 __attribute__((ext_vector_type(8)));
typedef short short4v __attribute__((ext_vector_type(4)));
typedef float f32x2 __attribute__((ext_vector_type(2)));
typedef float f32x4 __attribute__((ext_vector_type(4)));
typedef float f32x16 __attribute__((ext_vector_type(16)));
typedef unsigned uint2v __attribute__((ext_vector_type(2)));

__device__ inline short f2b(float x) {  // fp32 -> bf16, RNE-ish
  union { float f; unsigned u; } v; v.f = x;
  unsigned r = (v.u + 0x7FFF + ((v.u >> 16) & 1)) >> 16;
  return (short)r;
}
// packed bf16 convert: lo16 = bf16(a), hi16 = bf16(b), RNE, single VALU op
__device__ inline unsigned cvtpk(float a, float b) {
  unsigned r;
  asm("v_cvt_pk_bf16_f32 %0, %1, %2" : "=v"(r) : "v"(a), "v"(b));
  return r;
}
// v_permlane32_swap_b32: block-transpose primitive.
//   a' = {lanes 0-31: a[0:31],  lanes 32-63: b[0:31]}
//   b' = {lanes 0-31: a[32:63], lanes 32-63: b[32:63]}
__device__ inline void pswap(unsigned &a, unsigned &b) {
  uint2v r = __builtin_amdgcn_permlane32_swap(a, b, false, false);
  a = r[0]; b = r[1];
}
// LDS fragment load from 8B-aligned rows (stride 36 shorts): two b64 reads
__device__ inline short8 ldsfrag(const short* p) {
  short4v a = *(const short4v*)p;
  short4v b = *(const short4v*)(p + 4);
  short8 r;
  r[0] = a[0]; r[1] = a[1]; r[2] = a[2]; r[3] = a[3];
  r[4] = b[0]; r[5] = b[1]; r[6] = b[2]; r[7] = b[3];
  return r;
}
__device__ inline short8 mk8(unsigned a, unsigned b, unsigned c, unsigned d) {
  union { unsigned u[4]; short8 v; } t;
  t.u[0] = a; t.u[1] = b; t.u[2] = c; t.u[3] = d;
  return t.v;
}

// ---- fused QKV projection (MFMA), register-prefetched staging -------------
// which=0: Q (scaled by 1/sqrt(32)*log2(e), so attn uses exp2 directly)
//          token-major [bt][h][tok][32]
// which=1: K token-major [bt][h][tok][32]
// which=2: V d-major [bt][i][tok]
__global__ __launch_bounds__(256) void proj_fused(
    const float* __restrict__ query, const float* __restrict__ Wq,
    const float* __restrict__ key, const float* __restrict__ Wk,
    const float* __restrict__ value, const float* __restrict__ Wv,
    short* __restrict__ Qbf, short* __restrict__ Kbf,
    short* __restrict__ Vbf) {
  const int n0 = blockIdx.x * 64;
  const int which = blockIdx.y;
  const int bt = blockIdx.z;
  const int t = threadIdx.x;
  const int lane = t & 63, w = t >> 6;
  const int quad = lane >> 4, n16 = lane & 15;

  const float* X; const float* Wt; short* Y; int nchunk; float scl;
  if (which == 0) {
    X = query; Wt = Wq; Y = Qbf; nchunk = 8;
    scl = 0.17677669529663687f * 1.4426950408889634f;  // fold log2(e)
  } else if (which == 1) {
    X = key; Wt = Wk; Y = Kbf; nchunk = 4; scl = 1.0f;
  } else {
    X = value; Wt = Wv; Y = Vbf; nchunk = 4; scl = 1.0f;
  }
  const float* Xb = X + (size_t)bt * (nchunk * 32) * NTOK;

  __shared__ short Xs[64 * 36];   // [tok][d] bf16
  __shared__ short Ws[128 * 36];  // [i][d] bf16

  f32x4 acc[8];
#pragma unroll
  for (int i = 0; i < 8; ++i) acc[i] = (f32x4){0.f, 0.f, 0.f, 0.f};

  const int iw = t & 127, g = t >> 7;

  float xf0[4], xf1[4], wf0[8], wf1[8];
  auto loadX = [&](int cd) {
#pragma unroll
    for (int dp = 0; dp < 4; ++dp) {
      int dl = w * 8 + dp * 2;
      xf0[dp] = Xb[(size_t)(cd + dl) * NTOK + n0 + lane];
      xf1[dp] = Xb[(size_t)(cd + dl + 1) * NTOK + n0 + lane];
    }
  };
  auto loadW = [&](int cd) {
#pragma unroll
    for (int dp = 0; dp < 8; ++dp) {
      int dl = g * 16 + dp * 2;
      wf0[dp] = Wt[(size_t)(cd + dl) * INNER + iw];
      wf1[dp] = Wt[(size_t)(cd + dl + 1) * INNER + iw];
    }
  };
  loadX(0); loadW(0);

  for (int c = 0; c < nchunk; ++c) {
#pragma unroll
    for (int dp = 0; dp < 4; ++dp)
      *(unsigned*)&Xs[lane * 36 + w * 8 + dp * 2] = cvtpk(xf0[dp], xf1[dp]);
#pragma unroll
    for (int dp = 0; dp < 8; ++dp)
      *(unsigned*)&Ws[iw * 36 + g * 16 + dp * 2] = cvtpk(wf0[dp], wf1[dp]);
    __syncthreads();
    if (c + 1 < nchunk) { loadX((c + 1) * 32); loadW((c + 1) * 32); }
    if (which != 2) {
      short8 a[4], b[2];
#pragma unroll
      for (int tg = 0; tg < 4; ++tg)
        a[tg] = ldsfrag(&Xs[(tg * 16 + n16) * 36 + quad * 8]);
#pragma unroll
      for (int cg = 0; cg < 2; ++cg)
        b[cg] = ldsfrag(&Ws[(w * 32 + cg * 16 + n16) * 36 + quad * 8]);
#pragma unroll
      for (int tg = 0; tg < 4; ++tg)
#pragma unroll
        for (int cg = 0; cg < 2; ++cg)
          acc[tg * 2 + cg] = __builtin_amdgcn_mfma_f32_16x16x32_bf16(
              a[tg], b[cg], acc[tg * 2 + cg], 0, 0, 0);
    } else {
      short8 a[2], b[4];
#pragma unroll
      for (int ig = 0; ig < 2; ++ig)
        a[ig] = ldsfrag(&Ws[(w * 32 + ig * 16 + n16) * 36 + quad * 8]);
#pragma unroll
      for (int tg = 0; tg < 4; ++tg)
        b[tg] = ldsfrag(&Xs[(tg * 16 + n16) * 36 + quad * 8]);
#pragma unroll
      for (int ig = 0; ig < 2; ++ig)
#pragma unroll
        for (int tg = 0; tg < 4; ++tg)
          acc[ig * 4 + tg] = __builtin_amdgcn_mfma_f32_16x16x32_bf16(
              a[ig], b[tg], acc[ig * 4 + tg], 0, 0, 0);
    }
    __syncthreads();
  }

  if (which != 2) {
    short* Yb = Y + ((size_t)bt * NH + w) * NTOK * HD;
#pragma unroll
    for (int tg = 0; tg < 4; ++tg)
#pragma unroll
      for (int cg = 0; cg < 2; ++cg) {
        f32x4 a = acc[tg * 2 + cg];
#pragma unroll
        for (int r = 0; r < 4; ++r) {
          int tok = n0 + tg * 16 + quad * 4 + r;
          Yb[(size_t)tok * HD + cg * 16 + n16] = f2b(a[r] * scl);
        }
      }
  } else {
#pragma unroll
    for (int ig = 0; ig < 2; ++ig)
#pragma unroll
      for (int tg = 0; tg < 4; ++tg) {
        f32x4 a = acc[ig * 4 + tg];
#pragma unroll
        for (int r = 0; r < 4; ++r) {
          int irow = w * 32 + ig * 16 + quad * 4 + r;
          Y[((size_t)bt * INNER + irow) * NTOK + n0 + tg * 16 + n16] =
              f2b(a[r]);
        }
      }
  }
}

// ---- MFMA attention, 32x32 shape, TWO q-tiles per block (best: R6) --------
// grid 800: id>>5 = 64-q tile (25), id&31 = (bt,h). bid%8 = pair%8 keeps
// each pair's K/V XCD-local. Wave w covers k-range (416/416/384/384).
// Two 32-q tiles (A,B) share one K/V load stream: per 32k chunk the 4 L2
// loads amortize over 2x the issue work (8 MFMA + 32 exp2 ~ 310 cyc),
// covering per-chunk load latency at prefetch depth 1 (verified -12.7us
// vs 1-tile). Further levers (5-tile/R9, 4-blk/R10, depth-2/R11) all
// measured null-to-negative -- this configuration is the empirical
// (ILP, TLP) optimum. K-split partials combined via 17 KB LDS, 2 stages.
__global__ __launch_bounds__(256, 3) void attn_mfma(
    const short* __restrict__ Qb, const short* __restrict__ Kb,
    const short* __restrict__ Vb, short* __restrict__ Obf) {
  const int id = blockIdx.x;
  const int qt = id >> 5;
  const int pair = id & 31;
  const int bt = pair >> 2, h = pair & 3;
  const int wave = threadIdx.x >> 6, lane = threadIdx.x & 63;
  const int lh = lane >> 5, q32 = lane & 31;
  const int q0 = qt * 64;
  const size_t btok = ((size_t)bt * NH + h) * NTOK;
  const size_t bd = ((size_t)bt * NH + h) * HD;

  __shared__ float Cb[2][2][17][64];  // [tile][stage][row][lane], 17.4 KB

  const short* QpA = &Qb[(btok + q0 + q32) * HD + lh * 8];
  const short* QpB = QpA + 32 * HD;
  const short8 bqA0 = *(const short8*)(QpA);
  const short8 bqA1 = *(const short8*)(QpA + 16);
  const short8 bqB0 = *(const short8*)(QpB);
  const short8 bqB1 = *(const short8*)(QpB + 16);

  const int kstart = wave * 416 - (wave == 3 ? 32 : 0);
  const int nch = 13 - (wave >> 1);
  const short* Kp = &Kb[(btok + kstart + q32) * HD + lh * 8];
  const short* Vp = &Vb[(bd + q32) * NTOK + kstart + lh * 8];

  const f32x16 zero16 = {0.f, 0.f, 0.f, 0.f, 0.f, 0.f, 0.f, 0.f,
                         0.f, 0.f, 0.f, 0.f, 0.f, 0.f, 0.f, 0.f};
  f32x16 oA = zero16, oB = zero16;
  f32x2 lsA = {0.f, 0.f}, lsB = {0.f, 0.f};

  // exp2 + pack + cross-half exchange: S^T[k][q] regs -> PV B-operand frags.
  // reg r of sv holds S^T[k][q32], k = (r&3) + 8*(r>>2) + 4*lh.
  auto softmax_pack = [&](const f32x16& sv, f32x2& ls2, short8& pb0,
                          short8& pb1) {
    unsigned Pd[8];
#pragma unroll
    for (int g = 0; g < 4; ++g) {
      float e0 = __builtin_amdgcn_exp2f(sv[4 * g + 0]);
      float e1 = __builtin_amdgcn_exp2f(sv[4 * g + 1]);
      float e2 = __builtin_amdgcn_exp2f(sv[4 * g + 2]);
      float e3 = __builtin_amdgcn_exp2f(sv[4 * g + 3]);
      ls2 += (f32x2){e0, e1};
      ls2 += (f32x2){e2, e3};
      Pd[2 * g + 0] = cvtpk(e0, e1);
      Pd[2 * g + 1] = cvtpk(e2, e3);
    }
    // pswap(a,b): a.row1 <-> b.row0 =>
    //  Pd[0]' = {lo: own k0k1,        hi: lo-half's k8k9 }  = B dword0
    //  Pd[2]' = {lo: hi-half's k4k5,  hi: own k12k13     }  = B dword2
    pswap(Pd[0], Pd[2]);
    pswap(Pd[1], Pd[3]);
    pswap(Pd[4], Pd[6]);
    pswap(Pd[5], Pd[7]);
    pb0 = mk8(Pd[0], Pd[1], Pd[2], Pd[3]);
    pb1 = mk8(Pd[4], Pd[5], Pd[6], Pd[7]);
  };

  short8 ak0 = *(const short8*)(Kp);
  short8 ak1 = *(const short8*)(Kp + 16);
  short8 av0 = *(const short8*)(Vp);
  short8 av1 = *(const short8*)(Vp + 16);

  for (int i = 0; i < nch; ++i) {
    const size_t kn = (i + 1 < nch) ? (size_t)(i + 1) * 32 : 0;
    short8 nk0 = *(const short8*)(Kp + kn * HD);
    short8 nk1 = *(const short8*)(Kp + kn * HD + 16);
    short8 nv0 = *(const short8*)(Vp + kn);
    short8 nv1 = *(const short8*)(Vp + kn + 16);

    f32x16 sA = __builtin_amdgcn_mfma_f32_32x32x16_bf16(ak0, bqA0, zero16,
                                                        0, 0, 0);
    sA = __builtin_amdgcn_mfma_f32_32x32x16_bf16(ak1, bqA1, sA, 0, 0, 0);
    f32x16 sB = __builtin_amdgcn_mfma_f32_32x32x16_bf16(ak0, bqB0, zero16,
                                                        0, 0, 0);
    sB = __builtin_amdgcn_mfma_f32_32x32x16_bf16(ak1, bqB1, sB, 0, 0, 0);

    short8 pbA0, pbA1, pbB0, pbB1;
    softmax_pack(sA, lsA, pbA0, pbA1);
    softmax_pack(sB, lsB, pbB0, pbB1);

    oA = __builtin_amdgcn_mfma_f32_32x32x16_bf16(av0, pbA0, oA, 0, 0, 0);
    oA = __builtin_amdgcn_mfma_f32_32x32x16_bf16(av1, pbA1, oA, 0, 0, 0);
    oB = __builtin_amdgcn_mfma_f32_32x32x16_bf16(av0, pbB0, oB, 0, 0, 0);
    oB = __builtin_amdgcn_mfma_f32_32x32x16_bf16(av1, pbB1, oB, 0, 0, 0);

    ak0 = nk0; ak1 = nk1; av0 = nv0; av1 = nv1;
  }

  float lsumA = lsA[0] + lsA[1];
  lsumA += __shfl_xor(lsumA, 32);  // full row sum over both halves
  float lsumB = lsB[0] + lsB[1];
  lsumB += __shfl_xor(lsumB, 32);

  // two-stage combine across waves (17 KB LDS), both tiles in parallel
  auto dump = [&](int tl, int sidx, const f32x16& o, float ls) {
#pragma unroll
    for (int r = 0; r < 16; ++r) Cb[tl][sidx][r][lane] = o[r];
    Cb[tl][sidx][16][lane] = ls;
  };
  auto accum = [&](int tl, int sidx, f32x16& o, float& ls) {
#pragma unroll
    for (int r = 0; r < 16; ++r) o[r] += Cb[tl][sidx][r][lane];
    ls += Cb[tl][sidx][16][lane];
  };
  if (wave == 1) { dump(0, 0, oA, lsumA); dump(1, 0, oB, lsumB); }
  if (wave == 3) { dump(0, 1, oA, lsumA); dump(1, 1, oB, lsumB); }
  __syncthreads();
  if (wave == 0) { accum(0, 0, oA, lsumA); accum(1, 0, oB, lsumB); }
  if (wave == 2) { accum(0, 1, oA, lsumA); accum(1, 1, oB, lsumB); }
  __syncthreads();
  if (wave == 2) { dump(0, 0, oA, lsumA); dump(1, 0, oB, lsumB); }
  __syncthreads();
  if (wave == 0) {
    accum(0, 0, oA, lsumA);
    accum(1, 0, oB, lsumB);
    // O^T C-layout: col q = q32, row d = (r&3)+8*(r>>2)+4*lh
    const float invA = 1.f / lsumA;
    short* OpA =
        &Obf[((size_t)bt * NTOK + q0 + q32) * INNER + h * HD + lh * 4];
#pragma unroll
    for (int g = 0; g < 4; ++g) {
      unsigned d0 = cvtpk(oA[4 * g + 0] * invA, oA[4 * g + 1] * invA);
      unsigned d1 = cvtpk(oA[4 * g + 2] * invA, oA[4 * g + 3] * invA);
      *(uint2*)&OpA[8 * g] = make_uint2(d0, d1);
    }
    const float invB = 1.f / lsumB;
    short* OpB =
        &Obf[((size_t)bt * NTOK + q0 + 32 + q32) * INNER + h * HD + lh * 4];
#pragma unroll
    for (int g = 0; g < 4; ++g) {
      unsigned d0 = cvtpk(oB[4 * g + 0] * invB, oB[4 * g + 1] * invB);
      unsigned d1 = cvtpk(oB[4 * g + 2] * invB, oB[4 * g + 3] * invB);
      *(uint2*)&OpB[8 * g] = make_uint2(d0, d1);
    }
  }
}

// ---- output projection (MFMA). grid (25, 4, 8): 64 tok x 64 dout tiles ----
__global__ __launch_bounds__(256) void oproj_mfma(
    const short* __restrict__ Obf, const float* __restrict__ Wo,
    const float* __restrict__ bo, float* __restrict__ out) {
  const int tok0 = blockIdx.x * 64, d0 = blockIdx.y * 64;
  const int bt = blockIdx.z;
  const int t = threadIdx.x, lane = t & 63, w = t >> 6;
  const int quad = lane >> 4, n16 = lane & 15;
  __shared__ short Wos[64 * 36];  // [dout][i] bf16
  f32x4 acc[4];
#pragma unroll
  for (int i = 0; i < 4; ++i) acc[i] = (f32x4){0.f, 0.f, 0.f, 0.f};
  const int tok = tok0 + w * 16 + n16;  // always < 1600

  float wf0[4], wf1[4];
  short8 bfr;
  auto loadWo = [&](int c) {
#pragma unroll
    for (int dp = 0; dp < 4; ++dp) {
      int il = w * 8 + dp * 2;
      wf0[dp] = Wo[(size_t)(c * 32 + il) * QDIM + d0 + lane];
      wf1[dp] = Wo[(size_t)(c * 32 + il + 1) * QDIM + d0 + lane];
    }
  };
  auto loadB = [&](int c) {
    bfr = *(const short8*)&Obf[((size_t)bt * NTOK + tok) * INNER + c * 32 +
                               quad * 8];
  };
  loadWo(0); loadB(0);

  for (int c = 0; c < 4; ++c) {
#pragma unroll
    for (int dp = 0; dp < 4; ++dp)
      *(unsigned*)&Wos[lane * 36 + w * 8 + dp * 2] = cvtpk(wf0[dp], wf1[dp]);
    __syncthreads();
    short8 b0 = bfr;
    if (c < 3) { loadWo(c + 1); loadB(c + 1); }
#pragma unroll
    for (int ag = 0; ag < 4; ++ag) {
      short8 a = ldsfrag(&Wos[(ag * 16 + n16) * 36 + quad * 8]);
      acc[ag] = __builtin_amdgcn_mfma_f32_16x16x32_bf16(a, b0, acc[ag], 0, 0, 0);
    }
    __syncthreads();
  }

#pragma unroll
  for (int ag = 0; ag < 4; ++ag) {
    f32x4 a = acc[ag];
#pragma unroll
    for (int r = 0; r < 4; ++r) {
      int dout = d0 + ag * 16 + quad * 4 + r;
      out[((size_t)bt * QDIM + dout) * NTOK + tok] = a[r] + bo[dout];
    }
  }
}

extern "C" void kernel_launch(void* const* d_in, const int* in_sizes, int n_in,
                              void* d_out, int out_size, void* d_ws,
                              size_t ws_size, hipStream_t stream) {
  const float* query = (const float*)d_in[0];
  const float* key = (const float*)d_in[1];
  const float* value = (const float*)d_in[2];
  const float* Wq = (const float*)d_in[3];
  const float* Wk = (const float*)d_in[4];
  const float* Wv = (const float*)d_in[5];
  const float* Wo = (const float*)d_in[6];
  const float* bo = (const float*)d_in[7];
  float* out = (float*)d_out;

  const size_t arr = (size_t)BT_TOTAL * INNER * NTOK;
  short* Qbf = (short*)d_ws;
  short* Kbf = Qbf + arr;
  short* Vbf = Kbf + arr;
  short* Obf = Vbf + arr;

  proj_fused<<<dim3(25, 3, BT_TOTAL), 256, 0, stream>>>(
      query, Wq, key, Wk, value, Wv, Qbf, Kbf, Vbf);
  attn_mfma<<<dim3(800), 256, 0, stream>>>(Qbf, Kbf, Vbf, Obf);
  oproj_mfma<<<dim3(25, 4, BT_TOTAL), 256, 0, stream>>>(Obf, Wo, bo, out);
}